// Round 6
// baseline (129.071 us; speedup 1.0000x reference)
//
#include <hip/hip_runtime.h>
#include <hip/hip_cooperative_groups.h>

namespace cg = cooperative_groups;

#define N_NODES 1024
#define B_SZ 16
#define F_SZ 50

typedef float f32x4 __attribute__((ext_vector_type(4)));

// Single cooperative kernel.
// Phase 1 (first 64 blocks): port_has_track bits per (b,n) -> bits[b*N+n].
//   port_feature_mask is a known constant 0/1 matrix: features 0-22 all-zero;
//   port p sums exactly 7 features. Summing only nonzero features in
//   ascending-f order is bitwise identical to the reference's masked
//   accumulation (x + 0.0f == x exactly).
// grid.sync()
// Phase 2 (all 1024 blocks): block q owns 16 consecutive (b,i) rows ->
//   64 KB contiguous output; chip-wide write stream is linear like the
//   6.5 TB/s fill kernel. NT stores keep dir's L2 copies resident.
__global__ __launch_bounds__(256, 4) void fused_kernel(
        const float* __restrict__ nf,
        const int* __restrict__ dir,
        unsigned char* __restrict__ bits,
        float* __restrict__ out) {
    const int q = blockIdx.x;   // 1024 blocks
    const int t = threadIdx.x;  // 256 threads

    // ---- Phase 1: 16384 node-bit computations on the first 64 blocks ----
    const int tid = q * 256 + t;  // = b*N + n
    if (tid < B_SZ * N_NODES) {
        const float* r = nf + (size_t)tid * F_SZ;
        float f[27];
        #pragma unroll
        for (int x = 0; x < 27; ++x) f[x] = r[23 + x];  // features 23..49

        float a0 = (((((f[0]  + f[1])  + f[3])  + f[6])  + f[10]) + f[15]) + f[16];
        float a1 = (((((f[0]  + f[2])  + f[4])  + f[7])  + f[11]) + f[17]) + f[18];
        float a2 = (((((f[1]  + f[2])  + f[5])  + f[8])  + f[12]) + f[19]) + f[20];
        float a3 = (((((f[3]  + f[4])  + f[5])  + f[9])  + f[13]) + f[21]) + f[22];
        float a4 = (((((f[6]  + f[7])  + f[8])  + f[9])  + f[14]) + f[23]) + f[24];
        float a5 = (((((f[10] + f[11]) + f[12]) + f[13]) + f[14]) + f[25]) + f[26];

        unsigned m = 0;
        m |= (a0 > 0.0f) ? 1u  : 0u;
        m |= (a1 > 0.0f) ? 2u  : 0u;
        m |= (a2 > 0.0f) ? 4u  : 0u;
        m |= (a3 > 0.0f) ? 8u  : 0u;
        m |= (a4 > 0.0f) ? 16u : 0u;
        m |= (a5 > 0.0f) ? 32u : 0u;
        bits[tid] = (unsigned char)m;
    }

    __threadfence();           // device-scope release of bits
    cg::this_grid().sync();

    // ---- Phase 2: connect ----
    const int p0 = q * 16;         // first (b,i) row of this block
    const int b = p0 >> 10;        // constant within block (1024 % 16 == 0)

    // dst bits for this thread's 4 columns, batch b (block-invariant)
    uchar4 dv4 = ((const uchar4*)(bits + b * N_NODES))[t];
    unsigned tb[4] = {dv4.x, dv4.y, dv4.z, dv4.w};

    #pragma unroll
    for (int r8 = 0; r8 < 16; ++r8) {
        const int p = p0 + r8;
        const int i = p & (N_NODES - 1);

        int4 d = ((const int4*)(dir + (size_t)i * N_NODES))[t];
        int dvv[4] = {d.x, d.y, d.z, d.w};
        unsigned s = bits[b * N_NODES + i];  // wave-uniform scalar

        f32x4 o;
        #pragma unroll
        for (int k = 0; k < 4; ++k) {
            int dval = dvv[k];
            unsigned am = (dval != 6) ? 1u : 0u;
            unsigned ds = (unsigned)min(dval, 5);
            unsigned os = (unsigned)min((dval + 3) % 6, 5);
            o[k] = ((s >> ds) & (tb[k] >> os) & am & 1u) ? 1.0f : 0.0f;
        }
        __builtin_nontemporal_store(
            o, (f32x4*)(out + (size_t)p * N_NODES) + t);
    }
}

extern "C" void kernel_launch(void* const* d_in, const int* in_sizes, int n_in,
                              void* d_out, int out_size, void* d_ws, size_t ws_size,
                              hipStream_t stream) {
    const float* nf  = (const float*)d_in[0];    // (16, 1024, 50) f32
    const int*   dir = (const int*)d_in[1];      // (1024, 1024) i32
    float* out = (float*)d_out;                  // (16, 1024, 1024) f32
    unsigned char* bits = (unsigned char*)d_ws;  // 16 KB scratch, [b][n]

    void* args[] = {(void*)&nf, (void*)&dir, (void*)&bits, (void*)&out};
    hipLaunchCooperativeKernel((const void*)fused_kernel,
                               dim3(N_NODES), dim3(256), args, 0, stream);
}

// Round 7
// 25.742 us; speedup vs baseline: 5.0140x; 5.0140x over previous
//
#include <hip/hip_runtime.h>

#define N_NODES 1024
#define B_SZ 16
#define F_SZ 50
#define ROWS_PER_BLK 32           // 512 blocks = 16 batches x 32 row-chunks

typedef float f32x4 __attribute__((ext_vector_type(4)));

// Single kernel, no grid sync. Each block (batch b, 32-row chunk):
//   Phase 1: recompute port bits for ALL 1024 nodes of batch b into LDS.
//     nf is 3.2 MB -> L2-resident, so the 16x redundancy costs ~1.6 us
//     chip-wide. port_feature_mask is a known constant 0/1 matrix
//     (features 0-22 all-zero; port p sums exactly 7 features); summing
//     only nonzero features in ascending-f order is bitwise identical to
//     the reference's masked accumulation (x + 0.0f == x).
//   Phase 2: 32 rows x 4 KB = 128 KB contiguous output, consecutive blocks
//     adjacent -> chip-wide linear write stream (fill-kernel-like), plain
//     f32x4 stores through L2.
__global__ __launch_bounds__(256) void fused_kernel(
        const float* __restrict__ nf,
        const int* __restrict__ dir,
        float* __restrict__ out) {
    __shared__ unsigned char sbits[N_NODES];

    const int q = blockIdx.x;              // 512 blocks
    const int t = threadIdx.x;             // 256 threads
    const int b = q >> 5;                  // batch
    const int rowbase = (q & 31) * ROWS_PER_BLK;

    // ---- Phase 1: bits for all 1024 nodes of batch b ----
    #pragma unroll
    for (int c = 0; c < 4; ++c) {
        const int n = t + 256 * c;
        const float* r = nf + ((size_t)b * N_NODES + n) * F_SZ;
        float f[27];
        #pragma unroll
        for (int x = 0; x < 27; ++x) f[x] = r[23 + x];  // features 23..49

        float a0 = (((((f[0]  + f[1])  + f[3])  + f[6])  + f[10]) + f[15]) + f[16];
        float a1 = (((((f[0]  + f[2])  + f[4])  + f[7])  + f[11]) + f[17]) + f[18];
        float a2 = (((((f[1]  + f[2])  + f[5])  + f[8])  + f[12]) + f[19]) + f[20];
        float a3 = (((((f[3]  + f[4])  + f[5])  + f[9])  + f[13]) + f[21]) + f[22];
        float a4 = (((((f[6]  + f[7])  + f[8])  + f[9])  + f[14]) + f[23]) + f[24];
        float a5 = (((((f[10] + f[11]) + f[12]) + f[13]) + f[14]) + f[25]) + f[26];

        unsigned m = 0;
        m |= (a0 > 0.0f) ? 1u  : 0u;
        m |= (a1 > 0.0f) ? 2u  : 0u;
        m |= (a2 > 0.0f) ? 4u  : 0u;
        m |= (a3 > 0.0f) ? 8u  : 0u;
        m |= (a4 > 0.0f) ? 16u : 0u;
        m |= (a5 > 0.0f) ? 32u : 0u;
        sbits[n] = (unsigned char)m;
    }
    __syncthreads();

    // ---- Phase 2: connect, 32 rows of contiguous output ----
    uchar4 dv4 = *(const uchar4*)&sbits[t * 4];   // dst bits, this thread's 4 cols
    unsigned tb[4] = {dv4.x, dv4.y, dv4.z, dv4.w};

    const size_t obase = ((size_t)b * N_NODES + rowbase) * N_NODES;
    #pragma unroll 4
    for (int r = 0; r < ROWS_PER_BLK; ++r) {
        const int i = rowbase + r;
        const unsigned s = sbits[i];               // wave-uniform LDS broadcast

        int4 d = ((const int4*)(dir + (size_t)i * N_NODES))[t];
        int dvv[4] = {d.x, d.y, d.z, d.w};

        f32x4 o;
        #pragma unroll
        for (int k = 0; k < 4; ++k) {
            int dval = dvv[k];
            unsigned am = (dval != 6) ? 1u : 0u;
            unsigned ds = (unsigned)min(dval, 5);
            unsigned os = (unsigned)min((dval + 3) % 6, 5);
            o[k] = ((s >> ds) & (tb[k] >> os) & am & 1u) ? 1.0f : 0.0f;
        }
        *((f32x4*)(out + obase + (size_t)r * N_NODES) + t) = o;
    }
}

extern "C" void kernel_launch(void* const* d_in, const int* in_sizes, int n_in,
                              void* d_out, int out_size, void* d_ws, size_t ws_size,
                              hipStream_t stream) {
    const float* nf  = (const float*)d_in[0];    // (16, 1024, 50) f32
    const int*   dir = (const int*)d_in[1];      // (1024, 1024) i32
    float* out = (float*)d_out;                  // (16, 1024, 1024) f32

    fused_kernel<<<(B_SZ * N_NODES) / ROWS_PER_BLK, 256, 0, stream>>>(nf, dir, out);
}

// Round 8
// 21.213 us; speedup vs baseline: 6.0844x; 1.2135x over previous
//
#include <hip/hip_runtime.h>

#define N_NODES 1024
#define B_SZ 16
#define F_SZ 50

typedef float f32x4 __attribute__((ext_vector_type(4)));

// Kernel 1: port_has_track bits per (b, n), natural layout bits[b*N + n].
// port_feature_mask is a known constant 0/1 matrix: features 0-22 all-zero;
// port p sums exactly 7 features. Summing only nonzero features in
// ascending-f order is bitwise identical to the reference's masked
// accumulation (x + 0.0f == x exactly).
__global__ __launch_bounds__(64) void ports_kernel(
        const float* __restrict__ nf,
        unsigned char* __restrict__ bits) {
    int idx = blockIdx.x * 64 + threadIdx.x;  // b*N + n, 16384 total
    const float* r = nf + (size_t)idx * F_SZ;

    float f[27];
    #pragma unroll
    for (int q = 0; q < 27; ++q) f[q] = r[23 + q];  // features 23..49

    float a0 = (((((f[0]  + f[1])  + f[3])  + f[6])  + f[10]) + f[15]) + f[16];
    float a1 = (((((f[0]  + f[2])  + f[4])  + f[7])  + f[11]) + f[17]) + f[18];
    float a2 = (((((f[1]  + f[2])  + f[5])  + f[8])  + f[12]) + f[19]) + f[20];
    float a3 = (((((f[3]  + f[4])  + f[5])  + f[9])  + f[13]) + f[21]) + f[22];
    float a4 = (((((f[6]  + f[7])  + f[8])  + f[9])  + f[14]) + f[23]) + f[24];
    float a5 = (((((f[10] + f[11]) + f[12]) + f[13]) + f[14]) + f[25]) + f[26];

    unsigned m = 0;
    m |= (a0 > 0.0f) ? 1u  : 0u;
    m |= (a1 > 0.0f) ? 2u  : 0u;
    m |= (a2 > 0.0f) ? 4u  : 0u;
    m |= (a3 > 0.0f) ? 8u  : 0u;
    m |= (a4 > 0.0f) ? 16u : 0u;
    m |= (a5 > 0.0f) ? 32u : 0u;
    bits[idx] = (unsigned char)m;
}

// Kernel 2: out[b,i,j] = src_bit(b,i,dir') & dst_bit(b,j,opp') & (dir != 6)
// Fill-kernel-shaped: one (b,i) row per block (4 KB), one f32x4 per thread.
// Resident blocks are consecutive in dispatch order -> the chip-wide write
// front is a dense contiguous sliding window, like the 6.5 TB/s fill.
// Blocks sharing dir row i are 1024 apart -> same XCD -> dir L2-reuse.
__global__ __launch_bounds__(256) void connect_kernel(
        const int* __restrict__ dir,
        const unsigned char* __restrict__ bits,
        float* __restrict__ out) {
    const int bi = blockIdx.x;          // 16384 blocks = (b, i) pair
    const int t = threadIdx.x;          // columns [4t, 4t+3]
    const int b = bi >> 10;
    const int i = bi & (N_NODES - 1);

    int4 d = ((const int4*)(dir + (size_t)i * N_NODES))[t];
    uchar4 dv4 = ((const uchar4*)(bits + b * N_NODES))[t];
    unsigned tb[4] = {dv4.x, dv4.y, dv4.z, dv4.w};
    const unsigned s = bits[b * N_NODES + i];   // block-uniform

    int dvv[4] = {d.x, d.y, d.z, d.w};
    f32x4 o;
    #pragma unroll
    for (int k = 0; k < 4; ++k) {
        int dval = dvv[k];
        unsigned am = (dval != 6) ? 1u : 0u;
        unsigned ds = (unsigned)min(dval, 5);
        unsigned os = (unsigned)min((dval + 3) % 6, 5);
        o[k] = ((s >> ds) & (tb[k] >> os) & am & 1u) ? 1.0f : 0.0f;
    }
    __builtin_nontemporal_store(
        o, (f32x4*)(out + (size_t)bi * N_NODES) + t);
}

extern "C" void kernel_launch(void* const* d_in, const int* in_sizes, int n_in,
                              void* d_out, int out_size, void* d_ws, size_t ws_size,
                              hipStream_t stream) {
    const float* nf  = (const float*)d_in[0];    // (16, 1024, 50) f32
    const int*   dir = (const int*)d_in[1];      // (1024, 1024) i32
    float* out = (float*)d_out;                  // (16, 1024, 1024) f32
    unsigned char* bits = (unsigned char*)d_ws;  // 16 KB scratch, [b][n]

    ports_kernel<<<(B_SZ * N_NODES) / 64, 64, 0, stream>>>(nf, bits);
    connect_kernel<<<B_SZ * N_NODES, 256, 0, stream>>>(dir, bits, out);
}